// Round 3
// baseline (415.940 us; speedup 1.0000x reference)
//
#include <hip/hip_runtime.h>

// LRMU scan collapsed to out = U_rev^T @ P with P[j] = b·A^j via log-doubling.
// R3: persistent kernel, contention-free flag barrier (per-block flag stores,
// read-only polling) replacing the RMW-spin barrier that cost ~22 us each.
// U-phase folded into idle blocks of doubling phases 0..3 (8 barriers total).

#define SEQ_T 256
#define DIM 128
#define ORD 256
#define BMROWS 2048
#define NBLK 256

// float offsets into ws
#define OFF_U 0                        // U[t][bm]: 256*2048
#define OFF_P (SEQ_T * BMROWS)         // P[j][o]: 256*256
#define OFF_A0 (OFF_P + ORD * ORD)     // A-power ping
#define OFF_A1 (OFF_A0 + ORD * ORD)    // A-power pong
#define OFF_BAR (OFF_A1 + ORD * ORD)   // flags[256] + pad; gen at word 320

#define LD_RLX(p) \
  __hip_atomic_load((p), __ATOMIC_RELAXED, __HIP_MEMORY_SCOPE_AGENT)
#define ST_RLX(p, v) \
  __hip_atomic_store((p), (v), __ATOMIC_RELAXED, __HIP_MEMORY_SCOPE_AGENT)

// Contention-free grid barrier: arrival = store to OWN flag word (no RMW
// hotspot); block 0 polls all flags with its 256 threads (parallel, read-only)
// then releases a generation word; others poll gen read-only. __threadfence
// on both sides: release (L2 writeback past non-coherent XCD L2s) and
// acquire (invalidate stale L1/L2 before re-reading other blocks' data).
__device__ __forceinline__ void gbar(unsigned* flags, unsigned* gen,
                                     unsigned target) {
  __syncthreads();   // all waves drain vmcnt before signaling
  __threadfence();   // release
  const int tid = threadIdx.x;
  if (blockIdx.x == 0) {
    if (tid == 0) ST_RLX(&flags[0], target);
    while (LD_RLX(&flags[tid]) < target) __builtin_amdgcn_s_sleep(1);
    __syncthreads();
    if (tid == 0) ST_RLX(gen, target);
  } else if (tid == 0) {
    ST_RLX(&flags[blockIdx.x], target);
    while (LD_RLX(gen) < target) __builtin_amdgcn_s_sleep(1);
  }
  __syncthreads();
  __threadfence();   // acquire
}

__global__ __launch_bounds__(256) void lrmu_all(
    const float* __restrict__ x, const float* __restrict__ K,
    const float* __restrict__ A, const float* __restrict__ Bm,
    float* __restrict__ out, float* __restrict__ ws) {
  __shared__ __align__(16) float smem[4096];  // 16 KB, reused per phase
  float* U = ws + OFF_U;
  float* P = ws + OFF_P;
  float* A0 = ws + OFF_A0;
  float* A1 = ws + OFF_A1;
  unsigned* flags = (unsigned*)(ws + OFF_BAR);
  unsigned* gen = flags + 320;
  const int blk = blockIdx.x, tid = threadIdx.x;

  // ---- 8 phases: squaring (blks 0..127) + P-doubling + folded U chunks ----
  for (int k = 0; k < 8; ++k) {
    const float* Aold = (k == 0) ? A : ((k & 1) ? A0 : A1);
    float* Anew = (k & 1) ? A1 : A0;
    const int half = 1 << k;
    const int nsq = (k < 7) ? 128 : 0;  // k=7 needs no squaring
    const int rt = (k < 7) ? 8 : 2;     // doubling row-tile
    const int ndb = ((half + rt - 1) / rt) * 4;

    const float* L = nullptr;
    float* C = nullptr;
    int nrows = 0, c0 = 0;
    bool p0write = false;
    if (blk < nsq) {  // squaring: 8 rows x 64 cols, K split over 4 waves
      L = Aold + (blk >> 2) * 8 * ORD;
      C = Anew + (blk >> 2) * 8 * ORD;
      nrows = 8;
      c0 = (blk & 3) * 64;
    } else if (blk < nsq + ndb) {  // doubling: P[half+r] = P[r] @ Aold
      int di = blk - nsq;
      int rg = di >> 2;
      c0 = (di & 3) * 64;
      L = (k == 0) ? Bm : P + rg * rt * ORD;  // k=0: left row is b itself
      C = P + (half + rg * rt) * ORD;
      nrows = half - rg * rt;
      if (nrows > rt) nrows = rt;
      p0write = (k == 0) && (di == 0);  // also materialize P[0] = b
    } else if (k < 4 && blk >= 192) {
      // Folded U chunk: U[t][bm] = sum_d x[b][t][d] * K[d][m]
      int unit = k * 64 + (blk - 192);  // 256 units over 4 phases
      int b = unit >> 4, tc = unit & 15;
      float* xs = smem;  // [16][128]
      for (int idx = tid; idx < 16 * DIM; idx += 256)
        xs[idx] = x[(b * SEQ_T + tc * 16) * DIM + idx];
      __syncthreads();
      int m = tid & 127, th = tid >> 7;
      float acc[8] = {};
#pragma unroll 8
      for (int d = 0; d < DIM; ++d) {
        float kv = K[d * DIM + m];  // coalesced, L2-resident
#pragma unroll
        for (int r = 0; r < 8; ++r)
          acc[r] = fmaf(xs[(th * 8 + r) * DIM + d], kv, acc[r]);
      }
#pragma unroll
      for (int r = 0; r < 8; ++r)
        U[(tc * 16 + th * 8 + r) * BMROWS + b * DIM + m] = acc[r];
    }

    if (L) {
      float* ls = smem;          // [8][256] left rows (row-major)
      float* red = smem + 2048;  // [4][8][64] wave partials
      for (int idx = tid; idx < 8 * ORD; idx += 256) {
        int r = idx >> 8;
        ls[idx] = (r < nrows) ? L[idx] : 0.f;  // guard also keeps Bm in-bounds
      }
      __syncthreads();
      if (p0write) P[tid] = ls[tid];  // P[0][:] = b
      const int c = tid & 63, q = tid >> 6;  // wave q sums K in [q*64,q*64+64)
      float acc[8] = {};
      const float* col = Aold + c0 + c;
#pragma unroll 16
      for (int i2 = 0; i2 < 64; ++i2) {
        int i = q * 64 + i2;
        float av = col[i * ORD];  // coalesced 64-wide per wave
#pragma unroll
        for (int r = 0; r < 8; ++r)
          acc[r] = fmaf(ls[r * ORD + i], av, acc[r]);  // LDS broadcast
      }
#pragma unroll
      for (int r = 0; r < 8; ++r) red[(q * 8 + r) * 64 + c] = acc[r];
      __syncthreads();
      int rr = tid >> 6;
#pragma unroll
      for (int rh = 0; rh < 2; ++rh) {
        int r = rr + rh * 4;
        if (r < nrows) {
          float s = red[r * 64 + c] + red[(8 + r) * 64 + c] +
                    red[(16 + r) * 64 + c] + red[(24 + r) * 64 + c];
          C[r * ORD + c0 + c] = s;
        }
      }
    }
    gbar(flags, gen, k + 1);
  }

  // ---- Out phase: out[bm][o] = sum_t U[t][bm] * P[255-t][o] ----
  {
    float* us = smem;  // [256][8]
    int bm0 = blk * 8;
    for (int idx = tid; idx < SEQ_T * 8; idx += 256) {
      int t = idx >> 3, r = idx & 7;
      us[idx] = U[t * BMROWS + bm0 + r];
    }
    __syncthreads();
    float acc[8] = {};
    int c = tid;
#pragma unroll 16
    for (int t = 0; t < SEQ_T; ++t) {
      float pv = P[(SEQ_T - 1 - t) * ORD + c];  // coalesced, L2-resident
      const float4 u0 = *(const float4*)&us[t * 8];      // LDS broadcast
      const float4 u1 = *(const float4*)&us[t * 8 + 4];
      acc[0] = fmaf(u0.x, pv, acc[0]);
      acc[1] = fmaf(u0.y, pv, acc[1]);
      acc[2] = fmaf(u0.z, pv, acc[2]);
      acc[3] = fmaf(u0.w, pv, acc[3]);
      acc[4] = fmaf(u1.x, pv, acc[4]);
      acc[5] = fmaf(u1.y, pv, acc[5]);
      acc[6] = fmaf(u1.z, pv, acc[6]);
      acc[7] = fmaf(u1.w, pv, acc[7]);
    }
#pragma unroll
    for (int r = 0; r < 8; ++r) out[(bm0 + r) * ORD + c] = acc[r];
  }
}

extern "C" void kernel_launch(void* const* d_in, const int* in_sizes, int n_in,
                              void* d_out, int out_size, void* d_ws,
                              size_t ws_size, hipStream_t stream) {
  const float* x = (const float*)d_in[0];   // (16,256,128)
  const float* K = (const float*)d_in[1];   // (128,128)
  const float* A = (const float*)d_in[2];   // (256,256)
  const float* Bm = (const float*)d_in[3];  // (256,)
  float* out = (float*)d_out;               // (16, 32768)
  float* ws = (float*)d_ws;

  // zero barrier flags + generation (ws is re-poisoned 0xAA every call)
  hipMemsetAsync(ws + OFF_BAR, 0, 2048, stream);
  lrmu_all<<<NBLK, 256, 0, stream>>>(x, K, A, Bm, out, ws);
}

// Round 4
// 143.491 us; speedup vs baseline: 2.8987x; 2.8987x over previous
//
#include <hip/hip_runtime.h>

// LRMU scan collapsed to out = U_rev^T @ P with P[j] = b·A^j via log-doubling.
// R4: fence-free sync. Cross-block chain data (A-powers, P) uses relaxed
// AGENT-scope atomic load/store (cache-bypass to coherence point) so no
// __threadfence (= no buffer_wbl2/buffer_inv L2 flushes, the suspected
// ~25-45us/barrier cost in R2/R3) is ever needed. Chain runs on only 64
// blocks with a flag-array barrier (read-only polling); 192 other blocks do
// the U-GEMM with normal stores (kernel boundary syncs them). out-GEMM is a
// separate kernel.

#define SEQ_T 256
#define DIM 128
#define ORD 256
#define BMROWS 2048
#define NCHAIN 64

// float offsets into ws
#define OFF_U 0                         // U[t][bm]: 256*2048
#define OFF_P (SEQ_T * BMROWS)          // P[j][o]: 256*256
#define OFF_A0 (OFF_P + ORD * ORD)      // A-power ping
#define OFF_A1 (OFF_A0 + ORD * ORD)     // A-power pong
#define OFF_FLAGS (OFF_A1 + ORD * ORD)  // 64 flags, 64B stride (4 KB)

#define LD_A(p) \
  __hip_atomic_load((p), __ATOMIC_RELAXED, __HIP_MEMORY_SCOPE_AGENT)
#define ST_A(p, v) \
  __hip_atomic_store((p), (v), __ATOMIC_RELAXED, __HIP_MEMORY_SCOPE_AGENT)

// Barrier over the 64 chain blocks. No fences: data already at coherence
// point (sc1 stores drained by the vmcnt(0) each wave's __syncthreads
// implies + explicit waitcnt); readers use sc1 loads, so no stale caches.
// Arrival = store own flag; wave 0's lanes poll all 64 flags in parallel.
__device__ __forceinline__ void chain_bar(unsigned* flags, unsigned target) {
  __syncthreads();  // all waves drain their vmem (incl. sc1 stores)
  asm volatile("s_waitcnt vmcnt(0)" ::: "memory");
  const int t = threadIdx.x;
  if (t < NCHAIN) {  // exactly wave 0
    if (t == (int)blockIdx.x) ST_A(&flags[t * 16], target);
    while (LD_A(&flags[t * 16]) < target) __builtin_amdgcn_s_sleep(2);
  }
  __syncthreads();
}

__global__ __launch_bounds__(256) void lrmu_main(
    const float* __restrict__ x, const float* __restrict__ K,
    const float* __restrict__ A, const float* __restrict__ Bm,
    float* __restrict__ ws) {
  __shared__ __align__(16) float ls[6 * ORD];        // left rows, 6 KB
  __shared__ __align__(16) float red[4 * 6 * ORD];   // wave partials, 24 KB
  float* U = ws + OFF_U;
  float* P = ws + OFF_P;
  float* A0 = ws + OFF_A0;
  float* A1 = ws + OFF_A1;
  unsigned* flags = (unsigned*)(ws + OFF_FLAGS);
  const int blk = blockIdx.x, tid = threadIdx.x;

  if (blk >= NCHAIN) {
    // ---- U-GEMM on blocks 64..255: U[t][bm] = sum_d x[b][t][d]*K[d][m] ----
    float* xs = red;  // reuse 2048 floats of LDS
    for (int u = blk - NCHAIN; u < 256; u += 256 - NCHAIN) {
      int b = u >> 4, tc = u & 15;
      for (int idx = tid; idx < 16 * DIM; idx += 256)
        xs[idx] = x[(b * SEQ_T + tc * 16) * DIM + idx];
      __syncthreads();
      int m = tid & 127, th = tid >> 7;
      float acc[8] = {};
#pragma unroll 8
      for (int d = 0; d < DIM; ++d) {
        float kv = K[d * DIM + m];  // coalesced, L2-resident
#pragma unroll
        for (int r = 0; r < 8; ++r)
          acc[r] = fmaf(xs[(th * 8 + r) * DIM + d], kv, acc[r]);
      }
#pragma unroll
      for (int r = 0; r < 8; ++r)
        U[(tc * 16 + th * 8 + r) * BMROWS + b * DIM + m] = acc[r];
      __syncthreads();  // before next unit overwrites xs
    }
    return;
  }

  // ---- Chain on blocks 0..63: 8 steps, 7 internal barriers ----
  // Step k: Snew = S*S (rows 4*blk..4*blk+3; skipped at k=7) and
  //         P[half + d] = P[d] @ S for d = blk (+64), half = 2^k.
  const int lane = tid & 63, q = tid >> 6;
  for (int k = 0; k < 8; ++k) {
    const float* S = (k == 0) ? A : ((k & 1) ? A0 : A1);
    float* Snew = (k & 1) ? A1 : A0;
    const int half = 1 << k;
    const int nsr = (k < 7) ? 4 : 0;                       // squaring rows
    const int ndr = (k == 7) ? 2 : (blk < half ? 1 : 0);   // doubling rows
    const int tr = nsr + ndr;

    // stage left rows (squaring rows of S, then P rows / Bm) into ls
#pragma unroll
    for (int j = 0; j < 6; ++j) {
      int e = tid + 256 * j;
      int s = e >> 8, c = e & 255;
      float v = 0.f;
      if (s < nsr) {
        v = LD_A((float*)&S[(4 * blk + s) * ORD + c]);
      } else if (s - nsr < ndr) {
        int d = blk + 64 * (s - nsr);
        v = (k == 0) ? Bm[c] : LD_A(&P[d * ORD + c]);
      }
      ls[e] = v;
    }
    if (k == 0 && blk == 0) ST_A(&P[tid], Bm[tid]);  // P[0][:] = b
    __syncthreads();

    // wave q sums K-chunk [64q, 64q+64); lane covers cols lane + 64*j
    float acc[6][4];
#pragma unroll
    for (int s = 0; s < 6; ++s)
#pragma unroll
      for (int j = 0; j < 4; ++j) acc[s][j] = 0.f;
#pragma unroll 4
    for (int ii = 0; ii < 64; ++ii) {
      int i = (q << 6) + ii;
      float sv0 = LD_A((float*)&S[i * ORD + lane]);        // coalesced sc1
      float sv1 = LD_A((float*)&S[i * ORD + lane + 64]);
      float sv2 = LD_A((float*)&S[i * ORD + lane + 128]);
      float sv3 = LD_A((float*)&S[i * ORD + lane + 192]);
#pragma unroll
      for (int s = 0; s < 6; ++s) {
        float lv = ls[s * ORD + i];  // LDS broadcast
        acc[s][0] = fmaf(lv, sv0, acc[s][0]);
        acc[s][1] = fmaf(lv, sv1, acc[s][1]);
        acc[s][2] = fmaf(lv, sv2, acc[s][2]);
        acc[s][3] = fmaf(lv, sv3, acc[s][3]);
      }
    }
#pragma unroll
    for (int s = 0; s < 6; ++s)
#pragma unroll
      for (int j = 0; j < 4; ++j)
        red[(q * 6 + s) * ORD + (j << 6) + lane] = acc[s][j];
    __syncthreads();

    // reduce 4 wave-partials and store via sc1
#pragma unroll
    for (int j = 0; j < 6; ++j) {
      int o = tid + 256 * j;
      int s = o >> 8, c = o & 255;
      if (s < tr) {
        float sum = red[o] + red[1536 + o] + red[3072 + o] + red[4608 + o];
        float* dst;
        if (s < nsr) {
          dst = &Snew[(4 * blk + s) * ORD + c];
        } else {
          int d = blk + 64 * (s - nsr);
          dst = &P[(half + d) * ORD + c];
        }
        ST_A(dst, sum);
      }
    }
    if (k < 7) chain_bar(flags, (unsigned)(k + 1));
  }
}

// out[bm][o] = sum_t U[t][bm] * P[255-t][o]; 8 bm-rows x 256 cols per block.
// Separate kernel: the launch boundary provides device-wide coherence.
__global__ __launch_bounds__(256) void lrmu_out(
    const float* __restrict__ U, const float* __restrict__ P,
    float* __restrict__ out) {
  __shared__ __align__(16) float us[SEQ_T * 8];  // us[t][r], 8 KB
  int bm0 = blockIdx.x * 8;
  int tid = threadIdx.x;
  for (int idx = tid; idx < SEQ_T * 8; idx += 256) {
    int t = idx >> 3, r = idx & 7;
    us[idx] = U[t * BMROWS + bm0 + r];
  }
  __syncthreads();
  float acc[8] = {};
  int c = tid;
#pragma unroll 8
  for (int t = 0; t < SEQ_T; ++t) {
    float pv = P[(SEQ_T - 1 - t) * ORD + c];  // coalesced, L2/L3-resident
    const float4 u0 = *(const float4*)&us[t * 8];      // LDS broadcast
    const float4 u1 = *(const float4*)&us[t * 8 + 4];
    acc[0] = fmaf(u0.x, pv, acc[0]);
    acc[1] = fmaf(u0.y, pv, acc[1]);
    acc[2] = fmaf(u0.z, pv, acc[2]);
    acc[3] = fmaf(u0.w, pv, acc[3]);
    acc[4] = fmaf(u1.x, pv, acc[4]);
    acc[5] = fmaf(u1.y, pv, acc[5]);
    acc[6] = fmaf(u1.z, pv, acc[6]);
    acc[7] = fmaf(u1.w, pv, acc[7]);
  }
#pragma unroll
  for (int r = 0; r < 8; ++r) out[(bm0 + r) * ORD + c] = acc[r];
}

extern "C" void kernel_launch(void* const* d_in, const int* in_sizes, int n_in,
                              void* d_out, int out_size, void* d_ws,
                              size_t ws_size, hipStream_t stream) {
  const float* x = (const float*)d_in[0];   // (16,256,128)
  const float* K = (const float*)d_in[1];   // (128,128)
  const float* A = (const float*)d_in[2];   // (256,256)
  const float* Bm = (const float*)d_in[3];  // (256,)
  float* out = (float*)d_out;               // (16, 32768)
  float* ws = (float*)d_ws;

  // zero chain flags (ws is re-poisoned 0xAA before every timed call)
  hipMemsetAsync(ws + OFF_FLAGS, 0, 4096, stream);
  lrmu_main<<<256, 256, 0, stream>>>(x, K, A, Bm, ws);
  lrmu_out<<<BMROWS / 8, 256, 0, stream>>>(ws + OFF_U, ws + OFF_P, out);
}